// Round 14
// baseline (173.728 us; speedup 1.0000x reference)
//
#include <hip/hip_runtime.h>

// Problem constants (from reference setup_inputs):
//   image:  (B=4, H=512, W=640, C=16) fp32   (83.9 MB)
//   depth:  (B, H, W) fp32                    (5.2 MB)
//   proj:   (B, 4, 4) fp32
//   out:    (B, H, W, C) fp32                 (83.9 MB)
constexpr int B  = 4;
constexpr int H  = 512;
constexpr int Wd = 640;
constexpr int NPIX_IMG = H * Wd;
constexpr int BLOCK = 256;
constexpr int PIXB  = BLOCK / 4;            // 64 pixels per block
constexpr int BPR   = Wd / PIXB;            // 10 blocks per row (exact)
constexpr int BLOCKS_PER_IMG = H * BPR;     // 5120
constexpr int GRID  = B * BLOCKS_PER_IMG;   // 20480 blocks

constexpr int IMG_F4 = B * NPIX_IMG * 4;    // 5,242,880 float4s of image
constexpr int DEP_F4 = B * NPIX_IMG / 4;    // 327,680 float4s of depth
constexpr int WARM_GRID = 2048;             // 8 blocks/CU, grid-stride

static_assert(Wd % PIXB == 0, "block tiles a row exactly");

// Native vector type for nontemporal builtins (HIP_vector_type is rejected).
typedef float f32x4 __attribute__((ext_vector_type(4)));

// Round-14 theory: inline warming (r8/r13) can't work — warm traffic and
// consuming gathers run CONCURRENTLY, so gathers outrun the warm front and
// still miss to HBM (r8 FETCH stayed 97MB). Stream ordering gives what no
// inline scheme can: full completion of the warm before the consumer runs.
// Kernel 1 streams image+depth sequentially into L2/L3 at copy BW (~14us);
// kernel 2 (the unchanged resampler) then gathers from cache with ZERO HBM
// read involvement. Discriminator: if main-kernel FETCH collapses to ~0 but
// its time stays ~45us, the wall is structural latency, not HBM efficiency
// -> ROOFLINE. If time drops toward the write floor, theory confirmed.

__global__ __launch_bounds__(256) void warm_kernel(
    const float* __restrict__ image,
    const float* __restrict__ depth)
{
    const f32x4* img = (const f32x4*)image;
    const f32x4* dep = (const f32x4*)depth;
    const int stride = WARM_GRID * BLOCK;
    int i = blockIdx.x * BLOCK + threadIdx.x;

    f32x4 acc0 = {0.f, 0.f, 0.f, 0.f};
    f32x4 acc1 = {0.f, 0.f, 0.f, 0.f};
    // image: 5.24M f32x4, 10 grid-stride steps (unroll x2, indep accumulators)
    for (; i + stride < IMG_F4; i += 2 * stride) {
        f32x4 a = img[i];
        f32x4 b2 = img[i + stride];
        acc0 += a; acc1 += b2;
    }
    if (i < IMG_F4) acc0 += img[i];
    // depth: 327,680 f32x4, <1 step
    for (int j = blockIdx.x * BLOCK + threadIdx.x; j < DEP_F4; j += stride)
        acc1 += dep[j];

    acc0 += acc1;
    asm volatile("" :: "v"(acc0.x), "v"(acc0.y), "v"(acc0.z), "v"(acc0.w));
}

__global__ __launch_bounds__(256) void depth_project_kernel(
    const float* __restrict__ image,
    const float* __restrict__ depth,
    const float* __restrict__ proj,
    float4* __restrict__ out)
{
    const int blk = blockIdx.x;
    const int tix = threadIdx.x;

    // b, h block-uniform: SALU math, proj reads become s_loads.
    const int b   = blk / BLOCKS_PER_IMG;
    const int rem = blk % BLOCKS_PER_IMG;
    const int h   = rem / BPR;
    const int wb  = (rem % BPR) * PIXB;

    const int c4 = tix & 3;
    const int pl = tix >> 2;
    const int w  = wb + pl;
    const int pix = (b * H + h) * Wd + w;

    const float d = depth[pix];     // L2/L3 hit (warmed)

    const float* P = proj + b * 16; // uniform -> scalar loads
    const float x = (float)w;
    const float y = (float)h;

    float sx = (P[0] * x + P[1] * y + P[2])  * d + P[3];
    float sy = (P[4] * x + P[5] * y + P[6])  * d + P[7];
    float sz = (P[8] * x + P[9] * y + P[10]) * d + P[11];
    float cx = sx / sz;
    float cy = sy / sz;

    float x0f = floorf(cx), y0f = floorf(cy);
    float wx1 = cx - x0f,   wy1 = cy - y0f;
    float wx0 = 1.0f - wx1, wy0 = 1.0f - wy1;
    int x0 = (int)x0f, y0 = (int)y0f;
    int x1 = x0 + 1,   y1 = y0 + 1;

    float vx0 = (x0 >= 0 && x0 < Wd) ? 1.0f : 0.0f;
    float vx1 = (x1 >= 0 && x1 < Wd) ? 1.0f : 0.0f;
    float vy0 = (y0 >= 0 && y0 < H)  ? 1.0f : 0.0f;
    float vy1 = (y1 >= 0 && y1 < H)  ? 1.0f : 0.0f;

    int x0c = min(max(x0, 0), Wd - 1);
    int x1c = min(max(x1, 0), Wd - 1);
    int y0c = min(max(y0, 0), H - 1);
    int y1c = min(max(y1, 0), H - 1);

    float w00 = wy0 * wx0 * vy0 * vx0;
    float w01 = wy0 * wx1 * vy0 * vx1;
    float w10 = wy1 * wx0 * vy1 * vx0;
    float w11 = wy1 * wx1 * vy1 * vx1;

    // gathers: ALL warm in L2/L3 (stream-ordered warm kernel completed)
    const float4* img4 = (const float4*)image;
    const int base_b = b * (NPIX_IMG * 4);   // float4 units
    float4 g00 = img4[base_b + (y0c * Wd + x0c) * 4 + c4];
    float4 g01 = img4[base_b + (y0c * Wd + x1c) * 4 + c4];
    float4 g10 = img4[base_b + (y1c * Wd + x0c) * 4 + c4];
    float4 g11 = img4[base_b + (y1c * Wd + x1c) * 4 + c4];

    f32x4 r;
    r.x = g00.x * w00 + g01.x * w01 + g10.x * w10 + g11.x * w11;
    r.y = g00.y * w00 + g01.y * w01 + g10.y * w10 + g11.y * w11;
    r.z = g00.z * w00 + g01.z * w01 + g10.z * w10 + g11.z * w11;
    r.w = g00.w * w00 + g01.w * w01 + g10.w * w10 + g11.w * w11;

    // write-once stream: nontemporal so stores don't evict the warm image
    f32x4* out_v = (f32x4*)out;
    __builtin_nontemporal_store(r, out_v + pix * 4 + c4);
}

extern "C" void kernel_launch(void* const* d_in, const int* in_sizes, int n_in,
                              void* d_out, int out_size, void* d_ws, size_t ws_size,
                              hipStream_t stream) {
    const float* image = (const float*)d_in[0];
    const float* depth = (const float*)d_in[1];
    const float* proj  = (const float*)d_in[2];
    float4* out = (float4*)d_out;

    // stream-ordered: warm fully completes before the resampler starts
    warm_kernel<<<WARM_GRID, BLOCK, 0, stream>>>(image, depth);
    depth_project_kernel<<<GRID, BLOCK, 0, stream>>>(image, depth, proj, out);
}